// Round 1
// baseline (624.015 us; speedup 1.0000x reference)
//
#include <hip/hip_runtime.h>
#include <stdint.h>

#define NPTS   8192
#define NROWS  (NPTS * 16)
#define SLOPE  0.01f
#define BN_EPS 1e-5f

// ---- workspace layout (bytes) ----
#define OFF_Q      0u          // 8192x128 f32  (fea_last @ Wq^T + bq)
#define OFF_KP     4194304u    // 8192x128 f32
#define OFF_VP     8388608u    // 8192x128 f32
#define OFF_WT     12582912u   // 4 x 128x128 f32 transposed: WqT WkT WvT WlT (c-major: WT[c*128+o] = W[o*128+c])
#define OFF_XYZT   12845056u   // 6 x 8192 f32: xi yi zi | xl yl zl
#define OFF_IDX    13041664u   // 131072 i32 (8192 x 16 neighbor ids)
#define OFF_STATS  13565952u   // 4864 f32: stats1[256] bn1[256] stats2[16*256] bn2[256]
#define OFF_BIG    13585408u   // candD(8MB)+candI(8MB), later aliased by Y bf16 (33.5MB)
#define WS_NEED    47139840u

__device__ __forceinline__ unsigned int pack_bf2(float lo, float hi) {
  unsigned int a = __float_as_uint(lo);
  unsigned int b = __float_as_uint(hi);
  unsigned int ra = (a + 0x7fffu + ((a >> 16) & 1u)) >> 16;           // RNE bf16 of lo
  unsigned int rb = (b + 0x7fffu + ((b >> 16) & 1u)) & 0xffff0000u;   // RNE bf16 of hi in high half
  return ra | rb;
}
__device__ __forceinline__ void unpack2(unsigned int u, float& lo, float& hi) {
  lo = __uint_as_float(u << 16);
  hi = __uint_as_float(u & 0xffff0000u);
}
__device__ __forceinline__ float bf2f(unsigned short u) {
  return __uint_as_float(((unsigned int)u) << 16);
}

// ---------------- prep: transpose xyz + weights, zero stats ----------------
__global__ __launch_bounds__(256) void k_prep(const float* __restrict__ xyz_i,
                                              const float* __restrict__ xyz_last,
                                              const float* __restrict__ Wq,
                                              const float* __restrict__ Wk,
                                              const float* __restrict__ Wv,
                                              const float* __restrict__ Wl,
                                              float* __restrict__ xyzT,
                                              float* __restrict__ WT,
                                              float* __restrict__ stats_zero) {
  int t = blockIdx.x * 256 + threadIdx.x;   // 16384 threads
  if (t < NPTS) {
    xyzT[0 * NPTS + t] = xyz_i[t * 3 + 0];
    xyzT[1 * NPTS + t] = xyz_i[t * 3 + 1];
    xyzT[2 * NPTS + t] = xyz_i[t * 3 + 2];
    xyzT[3 * NPTS + t] = xyz_last[t * 3 + 0];
    xyzT[4 * NPTS + t] = xyz_last[t * 3 + 1];
    xyzT[5 * NPTS + t] = xyz_last[t * 3 + 2];
  }
  {
    int o = t >> 7, c = t & 127;
    WT[0 * 16384 + c * 128 + o] = Wq[t];
    WT[1 * 16384 + c * 128 + o] = Wk[t];
    WT[2 * 16384 + c * 128 + o] = Wv[t];
    WT[3 * 16384 + c * 128 + o] = Wl[t];
  }
  if (t < 4864) stats_zero[t] = 0.f;
}

// ---------------- projections: Out = A @ W^T + b (8192x128 @ 128x128) ----------------
// 64 rows/block, 256 threads, per-thread 4x8 tile, bf16 operands in LDS, f32 accum.
__global__ __launch_bounds__(256) void k_proj(const float* __restrict__ fea_i,
                                              const float* __restrict__ fea_last,
                                              const float* __restrict__ WT,
                                              const float* __restrict__ bq,
                                              const float* __restrict__ bk,
                                              const float* __restrict__ bv,
                                              float* __restrict__ Qo,
                                              float* __restrict__ Kpo,
                                              float* __restrict__ Vpo) {
  const int z = blockIdx.y;
  const float* A    = (z == 0) ? fea_last : fea_i;
  const float* WTz  = WT + z * 16384;
  const float* bias = (z == 0) ? bq : ((z == 1) ? bk : bv);
  float* Out        = (z == 0) ? Qo : ((z == 1) ? Kpo : Vpo);

  __shared__ unsigned short aT[128 * 72];    // [c][r], r<64, pad 72
  __shared__ unsigned short wT[128 * 128];   // [c][o] bf16
  const int t = threadIdx.x;
  const int rowbase = blockIdx.x * 64;
  {
    const int c = t & 127, half = t >> 7;
    #pragma unroll
    for (int i = 0; i < 16; ++i) {
      const int r = half * 32 + i * 2;
      float v0 = A[(size_t)(rowbase + r) * 128 + c];
      float v1 = A[(size_t)(rowbase + r + 1) * 128 + c];
      *(unsigned int*)&aT[c * 72 + r] = pack_bf2(v0, v1);
    }
    #pragma unroll
    for (int i = 0; i < 32; ++i) {
      const int e = i * 512 + t * 2;
      *(unsigned int*)&wT[e] = pack_bf2(WTz[e], WTz[e + 1]);
    }
  }
  __syncthreads();
  const int cg = t & 15, rg = t >> 4;
  const int p0 = cg * 8, r0 = rg * 4;
  float acc[4][8];
  #pragma unroll
  for (int i = 0; i < 4; ++i)
    #pragma unroll
    for (int j = 0; j < 8; ++j) acc[i][j] = 0.f;

  #pragma unroll 4
  for (int c = 0; c < 128; ++c) {
    uint2 au = *(const uint2*)&aT[c * 72 + r0];
    uint4 bu = *(const uint4*)&wT[c * 128 + p0];
    float a0, a1, a2, a3, b[8];
    unpack2(au.x, a0, a1); unpack2(au.y, a2, a3);
    unpack2(bu.x, b[0], b[1]); unpack2(bu.y, b[2], b[3]);
    unpack2(bu.z, b[4], b[5]); unpack2(bu.w, b[6], b[7]);
    #pragma unroll
    for (int j = 0; j < 8; ++j) {
      acc[0][j] = fmaf(a0, b[j], acc[0][j]);
      acc[1][j] = fmaf(a1, b[j], acc[1][j]);
      acc[2][j] = fmaf(a2, b[j], acc[2][j]);
      acc[3][j] = fmaf(a3, b[j], acc[3][j]);
    }
  }
  float bs[8];
  #pragma unroll
  for (int j = 0; j < 8; ++j) bs[j] = bias[p0 + j];
  #pragma unroll
  for (int i = 0; i < 4; ++i) {
    const int row = rowbase + r0 + i;
    float4 o0, o1;
    o0.x = acc[i][0] + bs[0]; o0.y = acc[i][1] + bs[1]; o0.z = acc[i][2] + bs[2]; o0.w = acc[i][3] + bs[3];
    o1.x = acc[i][4] + bs[4]; o1.y = acc[i][5] + bs[5]; o1.z = acc[i][6] + bs[6]; o1.w = acc[i][7] + bs[7];
    *(float4*)&Out[(size_t)row * 128 + p0]     = o0;
    *(float4*)&Out[(size_t)row * 128 + p0 + 4] = o1;
  }
}

// ---------------- KNN pass 1: per-(query,slice) top-16 via sorted insertion ----------------
__global__ __launch_bounds__(256) void k_knn_part(const float* __restrict__ xyzT,
                                                  float* __restrict__ candD,
                                                  int* __restrict__ candI) {
  const int T = blockIdx.x * 256 + threadIdx.x;   // 131072 threads
  const int q = T & (NPTS - 1);
  const int slice = T >> 13;                      // 16 slices of 512 points
  const float qx = xyzT[3 * NPTS + q];
  const float qy = xyzT[4 * NPTS + q];
  const float qz = xyzT[5 * NPTS + q];
  const float* xt = xyzT;
  const float* yt = xyzT + NPTS;
  const float* zt = xyzT + 2 * NPTS;

  float d[16]; int pi[16];
  #pragma unroll
  for (int j = 0; j < 16; ++j) { d[j] = 3.4e38f; pi[j] = 0; }

  const int base = slice * 512;
  for (int jj = 0; jj < 512; ++jj) {
    const int p = base + jj;
    float dx = qx - xt[p], dy = qy - yt[p], dz = qz - zt[p];
    float dd = fmaf(dx, dx, fmaf(dy, dy, dz * dz));
    if (dd < d[15]) {            // strict < : earlier (lower) index wins ties
      #pragma unroll
      for (int s = 15; s >= 1; --s) {
        bool cm1 = dd < d[s - 1];
        bool cs  = dd < d[s];
        d[s]  = cm1 ? d[s - 1]  : (cs ? dd : d[s]);
        pi[s] = cm1 ? pi[s - 1] : (cs ? p  : pi[s]);
      }
      bool c0 = dd < d[0];
      d[0]  = c0 ? dd : d[0];
      pi[0] = c0 ? p  : pi[0];
    }
  }
  #pragma unroll
  for (int j = 0; j < 16; ++j) {
    candD[(size_t)(slice * 16 + j) * NPTS + q] = d[j];
    candI[(size_t)(slice * 16 + j) * NPTS + q] = pi[j];
  }
}

// ---------------- KNN pass 2: merge 16 slices, lex (dist,idx) order ----------------
__global__ __launch_bounds__(256) void k_knn_merge(const float* __restrict__ candD,
                                                   const int* __restrict__ candI,
                                                   int* __restrict__ idxo) {
  const int q = blockIdx.x * 256 + threadIdx.x;   // 8192 threads
  unsigned long long key[16];
  #pragma unroll
  for (int j = 0; j < 16; ++j) key[j] = ~0ull;
  for (int s = 0; s < 256; ++s) {
    float dv = candD[(size_t)s * NPTS + q];
    unsigned int pv = (unsigned int)candI[(size_t)s * NPTS + q];
    unsigned long long kk = ((unsigned long long)__float_as_uint(dv) << 32) | pv;
    if (kk < key[15]) {
      #pragma unroll
      for (int u = 15; u >= 1; --u) {
        bool cm1 = kk < key[u - 1];
        bool cs  = kk < key[u];
        key[u] = cm1 ? key[u - 1] : (cs ? kk : key[u]);
      }
      key[0] = (kk < key[0]) ? kk : key[0];
    }
  }
  #pragma unroll
  for (int j = 0; j < 16; ++j) idxo[q * 16 + j] = (int)(key[j] & 0xffffffffull);
}

// ---------------- stats1: per-channel sum/sumsq of w = Q[n] - Kp[idx] ----------------
__global__ __launch_bounds__(256) void k_stats1(const float* __restrict__ Q,
                                                const float* __restrict__ Kp,
                                                const int* __restrict__ idx,
                                                float* __restrict__ stats1) {
  const int t = threadIdx.x;
  const int o = t & 127, h = t >> 7;
  float s = 0.f, q2 = 0.f;
  const int base = blockIdx.x * 512;
  for (int i = 0; i < 256; ++i) {
    const int row = base + i * 2 + h;
    const int n = row >> 4;
    const int pid = idx[row];
    float w = Q[(size_t)n * 128 + o] - Kp[(size_t)pid * 128 + o];
    s += w; q2 += w * w;
  }
  __shared__ float rs[256], rq[256];
  rs[t] = s; rq[t] = q2;
  __syncthreads();
  if (t < 128) {
    atomicAdd(&stats1[o],       rs[t] + rs[t + 128]);
    atomicAdd(&stats1[128 + o], rq[t] + rq[t + 128]);
  }
}

// ---------------- BN finalize: scale/shift from (sum,sumsq) ----------------
__global__ void k_bnfin(const float* __restrict__ stats, int nrep, float invM,
                        const float* __restrict__ gamma, const float* __restrict__ beta,
                        float* __restrict__ bn) {
  const int o = threadIdx.x;  // 128
  float s = 0.f, q = 0.f;
  for (int r = 0; r < nrep; ++r) { s += stats[r * 256 + o]; q += stats[r * 256 + 128 + o]; }
  float mean = s * invM;
  float var  = fmaf(-mean, mean, q * invM);     // biased variance
  float sc = gamma[o] * rsqrtf(var + BN_EPS);
  bn[o]       = sc;
  bn[128 + o] = fmaf(-mean, sc, beta[o]);
}

// ---------------- mid GEMM: y = leaky(bn1(w)) @ Wl^T + bl ; + BN2 stats; y -> bf16 ----------------
__global__ __launch_bounds__(256) void k_mid(const float* __restrict__ Q,
                                             const float* __restrict__ Kp,
                                             const int* __restrict__ idx,
                                             const float* __restrict__ WTl,
                                             const float* __restrict__ bl,
                                             const float* __restrict__ bn1,
                                             float* __restrict__ stats2,
                                             unsigned short* __restrict__ Y) {
  __shared__ unsigned short aT[128 * 72];
  __shared__ unsigned short wT[128 * 128];
  __shared__ float red[4 * 16 * 16];
  const int t = threadIdx.x;
  const int rowbase = blockIdx.x * 64;
  {
    const int c = t & 127, half = t >> 7;
    const float s1 = bn1[c], sh1 = bn1[128 + c];
    #pragma unroll
    for (int i = 0; i < 16; ++i) {
      const int r = half * 32 + i * 2;
      const int g0 = rowbase + r, g1 = g0 + 1;
      const int n0 = g0 >> 4, n1 = g1 >> 4;
      const int pa = idx[g0], pb = idx[g1];
      float w0 = Q[(size_t)n0 * 128 + c] - Kp[(size_t)pa * 128 + c];
      float w1 = Q[(size_t)n1 * 128 + c] - Kp[(size_t)pb * 128 + c];
      float x0 = fmaf(w0, s1, sh1); x0 = (x0 >= 0.f) ? x0 : SLOPE * x0;
      float x1 = fmaf(w1, s1, sh1); x1 = (x1 >= 0.f) ? x1 : SLOPE * x1;
      *(unsigned int*)&aT[c * 72 + r] = pack_bf2(x0, x1);
    }
    #pragma unroll
    for (int i = 0; i < 32; ++i) {
      const int e = i * 512 + t * 2;
      *(unsigned int*)&wT[e] = pack_bf2(WTl[e], WTl[e + 1]);
    }
  }
  __syncthreads();
  const int cg = t & 15, rg = t >> 4;
  const int p0 = cg * 8, r0 = rg * 4;
  float acc[4][8];
  #pragma unroll
  for (int i = 0; i < 4; ++i)
    #pragma unroll
    for (int j = 0; j < 8; ++j) acc[i][j] = 0.f;

  #pragma unroll 4
  for (int c = 0; c < 128; ++c) {
    uint2 au = *(const uint2*)&aT[c * 72 + r0];
    uint4 bu = *(const uint4*)&wT[c * 128 + p0];
    float a0, a1, a2, a3, b[8];
    unpack2(au.x, a0, a1); unpack2(au.y, a2, a3);
    unpack2(bu.x, b[0], b[1]); unpack2(bu.y, b[2], b[3]);
    unpack2(bu.z, b[4], b[5]); unpack2(bu.w, b[6], b[7]);
    #pragma unroll
    for (int j = 0; j < 8; ++j) {
      acc[0][j] = fmaf(a0, b[j], acc[0][j]);
      acc[1][j] = fmaf(a1, b[j], acc[1][j]);
      acc[2][j] = fmaf(a2, b[j], acc[2][j]);
      acc[3][j] = fmaf(a3, b[j], acc[3][j]);
    }
  }
  float bs[8];
  #pragma unroll
  for (int j = 0; j < 8; ++j) bs[j] = bl[p0 + j];
  float ssum[8], sqq[8];
  #pragma unroll
  for (int j = 0; j < 8; ++j) { ssum[j] = 0.f; sqq[j] = 0.f; }
  #pragma unroll
  for (int i = 0; i < 4; ++i) {
    float zv[8];
    #pragma unroll
    for (int j = 0; j < 8; ++j) { zv[j] = acc[i][j] + bs[j]; ssum[j] += zv[j]; sqq[j] += zv[j] * zv[j]; }
    uint4 st;
    st.x = pack_bf2(zv[0], zv[1]); st.y = pack_bf2(zv[2], zv[3]);
    st.z = pack_bf2(zv[4], zv[5]); st.w = pack_bf2(zv[6], zv[7]);
    *(uint4*)&Y[(size_t)(rowbase + r0 + i) * 128 + p0] = st;
  }
  // reduce stats over the 4 rgrps within each wave (lanes xor 16,32), then across waves via LDS
  #pragma unroll
  for (int j = 0; j < 8; ++j) {
    ssum[j] += __shfl_xor(ssum[j], 16); ssum[j] += __shfl_xor(ssum[j], 32);
    sqq[j]  += __shfl_xor(sqq[j], 16);  sqq[j]  += __shfl_xor(sqq[j], 32);
  }
  const int lane = t & 63, wave = t >> 6;
  if (lane < 16) {
    #pragma unroll
    for (int j = 0; j < 8; ++j) {
      red[(wave * 16 + lane) * 16 + j]     = ssum[j];
      red[(wave * 16 + lane) * 16 + 8 + j] = sqq[j];
    }
  }
  __syncthreads();
  {
    const int cg2 = t >> 4, v = t & 15;
    float tot = red[(0 * 16 + cg2) * 16 + v] + red[(1 * 16 + cg2) * 16 + v]
              + red[(2 * 16 + cg2) * 16 + v] + red[(3 * 16 + cg2) * 16 + v];
    const int p = cg2 * 8 + (v & 7);
    const int stat = v >> 3;
    atomicAdd(&stats2[(blockIdx.x & 15) * 256 + stat * 128 + p], tot);
  }
}

// ---------------- epilogue: BN2+leaky -> softmax over K -> weighted V gather ----------------
__global__ __launch_bounds__(128) void k_epi(const unsigned short* __restrict__ Y,
                                             const float* __restrict__ Vp,
                                             const int* __restrict__ idx,
                                             const float* __restrict__ bn2,
                                             float* __restrict__ out) {
  const int n = blockIdx.x;
  const int p = threadIdx.x;
  const float s2 = bn2[p], sh2 = bn2[128 + p];
  float z[16];
  #pragma unroll
  for (int k = 0; k < 16; ++k) {
    float yv = bf2f(Y[(size_t)(n * 16 + k) * 128 + p]);
    float v = fmaf(yv, s2, sh2);
    z[k] = (v >= 0.f) ? v : SLOPE * v;
  }
  float m = z[0];
  #pragma unroll
  for (int k = 1; k < 16; ++k) m = fmaxf(m, z[k]);
  float acc = 0.f, denom = 0.f;
  #pragma unroll
  for (int k = 0; k < 16; ++k) {
    float e = __expf(z[k] - m);
    denom += e;
    const int pid = idx[n * 16 + k];
    acc = fmaf(e, Vp[(size_t)pid * 128 + p], acc);
  }
  out[(size_t)n * 128 + p] = acc / denom;
}

extern "C" void kernel_launch(void* const* d_in, const int* in_sizes, int n_in,
                              void* d_out, int out_size, void* d_ws, size_t ws_size,
                              hipStream_t stream) {
  const float* fea_i    = (const float*)d_in[0];
  const float* fea_last = (const float*)d_in[1];
  const float* xyz_i    = (const float*)d_in[2];
  const float* xyz_last = (const float*)d_in[3];
  // d_in[4] = batch (single batch, unused)
  const float* Wq = (const float*)d_in[5];
  const float* bq = (const float*)d_in[6];
  const float* Wk = (const float*)d_in[7];
  const float* bk = (const float*)d_in[8];
  const float* Wv = (const float*)d_in[9];
  const float* bv = (const float*)d_in[10];
  const float* g1 = (const float*)d_in[11];
  const float* b1 = (const float*)d_in[12];
  const float* Wl = (const float*)d_in[13];
  const float* bl = (const float*)d_in[14];
  const float* g2 = (const float*)d_in[15];
  const float* b2 = (const float*)d_in[16];

  if (ws_size < (size_t)WS_NEED) return;  // need ~45 MiB scratch

  char* ws = (char*)d_ws;
  float* Q      = (float*)(ws + OFF_Q);
  float* Kp     = (float*)(ws + OFF_KP);
  float* Vp     = (float*)(ws + OFF_VP);
  float* WT     = (float*)(ws + OFF_WT);
  float* xyzT   = (float*)(ws + OFF_XYZT);
  int*   idxb   = (int*)  (ws + OFF_IDX);
  float* stats1 = (float*)(ws + OFF_STATS);
  float* bn1    = stats1 + 256;
  float* stats2 = stats1 + 512;
  float* bn2    = stats1 + 512 + 4096;
  float* candD  = (float*)(ws + OFF_BIG);
  int*   candI  = (int*)  (ws + OFF_BIG + 8388608u);
  unsigned short* Y = (unsigned short*)(ws + OFF_BIG);  // aliases cand buffers (dead by then)

  k_prep<<<64, 256, 0, stream>>>(xyz_i, xyz_last, Wq, Wk, Wv, Wl, xyzT, WT, stats1);
  k_proj<<<dim3(128, 3), 256, 0, stream>>>(fea_i, fea_last, WT, bq, bk, bv, Q, Kp, Vp);
  k_knn_part<<<512, 256, 0, stream>>>(xyzT, candD, candI);
  k_knn_merge<<<32, 256, 0, stream>>>(candD, candI, idxb);
  k_stats1<<<256, 256, 0, stream>>>(Q, Kp, idxb, stats1);
  k_bnfin<<<1, 128, 0, stream>>>(stats1, 1, 1.f / (float)NROWS, g1, b1, bn1);
  k_mid<<<2048, 256, 0, stream>>>(Q, Kp, idxb, WT + 3 * 16384, bl, bn1, stats2, Y);
  k_bnfin<<<1, 128, 0, stream>>>(stats2, 16, 1.f / (float)NROWS, g2, b2, bn2);
  k_epi<<<8192, 128, 0, stream>>>(Y, Vp, idxb, bn2, (float*)d_out);
}